// Round 6
// baseline (551.153 us; speedup 1.0000x reference)
//
#include <hip/hip_runtime.h>
#include <math.h>

typedef _Float16 f16;
typedef _Float16 f16x4 __attribute__((ext_vector_type(4)));
typedef _Float16 f16x8 __attribute__((ext_vector_type(8)));
typedef float    f32x4 __attribute__((ext_vector_type(4)));

#define NSEQ 1024
#define CD   128
#define LT   136   // pre-kernel LDS f16 row stride (272 B = 17*16 B, keeps b128 alignment)

// khs: [bh][g16 0..63][cs 0..3][lane 0..63][j 0..7]   (131072 f16 per bh)
//   value = Ktr[key = (g16>>1)*32 + 8*(lq>>2) + 4*(g16&1) + (lq&3)][c = cs*32+quad*8+j]
// vhs: [bh][k32 0..31][cb 0..7][lane 0..63][j 0..7]
//   value = Vtr[key = k32*32 + quad*8 + j][c = cb*16 + lq]
// Both are exact MFMA fragment order: a wave's frag load = base + lane*16B (coalesced 1KB).

__global__ __launch_bounds__(256)
void ipa_pre(const float* __restrict__ kg, const float* __restrict__ vg,
             const float* __restrict__ Lm, f16* __restrict__ khs, f16* __restrict__ vhs)
{
    __shared__ float LL[64 * 16];
    __shared__ __align__(16) f16 Kt[64 * LT];
    __shared__ __align__(16) f16 Vt[64 * LT];
    const int bx = blockIdx.x, nt = blockIdx.y, tid = threadIdx.x;
    const int bh = ((bx & 7) << 3) | (bx >> 3);   // XCD x <-> bh 8x..8x+7 (matches attn)
    const int b  = bh >> 3;
    const float* Lb = Lm + ((size_t)b * NSEQ + nt * 64) * 16;
    for (int t = tid; t < 64 * 16; t += 256) LL[t] = Lb[t];
    __syncthreads();

    const size_t base = ((size_t)bh * NSEQ + nt * 64) * CD;
    #pragma unroll
    for (int it = 0; it < 8; ++it) {
        int g = it * 256 + tid;
        int row = g >> 5, cg = g & 31;
        size_t idx = base + row * CD + cg * 4;
        const float* Lr = &LL[row * 16];
        float4 xk = *(const float4*)(kg + idx);
        float4 xv = *(const float4*)(vg + idx);
        float4 yk = xk, yv = xv;
        if (cg >= 2) {
            float t0 = xk.x, t1 = -xk.y, t2 = -xk.z, t3 = -xk.w;   // K: M = L^T eta
            yk.x = Lr[0]*t0 + Lr[4]*t1 + Lr[8] *t2 + Lr[12]*t3;
            yk.y = Lr[1]*t0 + Lr[5]*t1 + Lr[9] *t2 + Lr[13]*t3;
            yk.z = Lr[2]*t0 + Lr[6]*t1 + Lr[10]*t2 + Lr[14]*t3;
            yk.w = Lr[3]*t0 + Lr[7]*t1 + Lr[11]*t2 + Lr[15]*t3;
            t0 = xv.x; t1 = -xv.y; t2 = -xv.z; t3 = -xv.w;         // V: M = eta L^T eta
            yv.x =  (Lr[0]*t0 + Lr[4]*t1 + Lr[8] *t2 + Lr[12]*t3);
            yv.y = -(Lr[1]*t0 + Lr[5]*t1 + Lr[9] *t2 + Lr[13]*t3);
            yv.z = -(Lr[2]*t0 + Lr[6]*t1 + Lr[10]*t2 + Lr[14]*t3);
            yv.w = -(Lr[3]*t0 + Lr[7]*t1 + Lr[11]*t2 + Lr[15]*t3);
        }
        f16x4 hk = {(f16)yk.x, (f16)yk.y, (f16)yk.z, (f16)yk.w};
        f16x4 hv = {(f16)yv.x, (f16)yv.y, (f16)yv.z, (f16)yv.w};
        *(f16x4*)&Kt[row * LT + cg * 4] = hk;
        *(f16x4*)&Vt[row * LT + cg * 4] = hv;
    }
    __syncthreads();

    // staged K out (b128 LDS read -> fully coalesced global store)
    f16* kout = khs + (size_t)bh * 131072 + (size_t)nt * 4 * 4 * 512;
    #pragma unroll
    for (int it = 0; it < 4; ++it) {
        int slot = it * 256 + tid;                 // (g16l, cs, L)
        int g16l = slot >> 8, cs = (slot >> 6) & 3, L = slot & 63;
        int lq = L & 15, quad = L >> 4;
        int keyl = ((g16l >> 1) << 5) + ((lq >> 2) << 3) + ((g16l & 1) << 2) + (lq & 3);
        f16x8 kv = *(const f16x8*)&Kt[keyl * LT + cs * 32 + quad * 8];
        *(f16x8*)(kout + (g16l * 4 + cs) * 512 + L * 8) = kv;
    }
    // staged V^T out (scalar LDS column reads -> coalesced global store)
    f16* vout = vhs + (size_t)bh * 131072 + (size_t)nt * 2 * 8 * 512;
    #pragma unroll
    for (int it = 0; it < 4; ++it) {
        int slot = it * 256 + tid;                 // (k32l, cb, L)
        int k32l = slot >> 9, cb = (slot >> 6) & 7, L = slot & 63;
        int lq = L & 15, quad = L >> 4;
        int c = cb * 16 + lq;
        f16x8 o;
        #pragma unroll
        for (int j = 0; j < 8; ++j)
            o[j] = Vt[(k32l * 32 + quad * 8 + j) * LT + c];
        *(f16x8*)(vout + (k32l * 8 + cb) * 512 + L * 8) = o;
    }
}

// ------- attention: split-K streaming (2 waves/block, keys halved), LDS combine -------
__global__ __launch_bounds__(128, 4)
void ipa_attn(const float* __restrict__ qg, const f16* __restrict__ khs,
              const f16* __restrict__ vhs, const float* __restrict__ Lm,
              float* __restrict__ out)
{
    __shared__ float OX[2][32][68];    // channel-half exchange [wave][qlocal][c(+pad)]
    __shared__ float MLx[2][2][32];    // [wave][m/l][qlocal]

    const int n = blockIdx.x;                          // 0..2047
    const int bh = ((n & 7) << 3) | ((n >> 3) & 7);    // XCD n%8 owns bh 8x..8x+7
    const int b  = bh >> 3;
    const int tid = threadIdx.x;
    const int w = tid >> 6, lane = tid & 63, lq = lane & 15, quad = lane >> 4;
    const int q0 = (n >> 6) * 32;                      // 32 q-groups per bh
    const f16* kbh = khs + (size_t)bh * 131072;
    const f16* vbh = vhs + (size_t)bh * 131072;
    const float sc2 = 0.12751744154226873f;            // (1/sqrt(128)) * log2(e)

    // ---- Q: load fp32, transform (M = eta L^T eta) per-lane, scale, make frags ----
    f16x8 qf[2][4];
    #pragma unroll
    for (int u = 0; u < 2; ++u) {
        int qrow = q0 + u * 16 + lq;
        const float* Lr = Lm + ((size_t)b * NSEQ + qrow) * 16;
        const float* qp = qg + ((size_t)bh * NSEQ + qrow) * CD;
        float Lv[16];
        #pragma unroll
        for (int i = 0; i < 4; ++i) *(float4*)&Lv[i*4] = *(const float4*)(Lr + i*4);
        #pragma unroll
        for (int cs = 0; cs < 4; ++cs) {
            int c0 = cs * 32 + quad * 8;
            float4 x0 = *(const float4*)(qp + c0);
            float4 x1 = *(const float4*)(qp + c0 + 4);
            if (c0 >= 8) {
                float t0 = x0.x, t1 = -x0.y, t2 = -x0.z, t3 = -x0.w;
                float4 y;
                y.x =  (Lv[0]*t0 + Lv[4]*t1 + Lv[8] *t2 + Lv[12]*t3);
                y.y = -(Lv[1]*t0 + Lv[5]*t1 + Lv[9] *t2 + Lv[13]*t3);
                y.z = -(Lv[2]*t0 + Lv[6]*t1 + Lv[10]*t2 + Lv[14]*t3);
                y.w = -(Lv[3]*t0 + Lv[7]*t1 + Lv[11]*t2 + Lv[15]*t3);
                x0 = y;
                t0 = x1.x; t1 = -x1.y; t2 = -x1.z; t3 = -x1.w;
                y.x =  (Lv[0]*t0 + Lv[4]*t1 + Lv[8] *t2 + Lv[12]*t3);
                y.y = -(Lv[1]*t0 + Lv[5]*t1 + Lv[9] *t2 + Lv[13]*t3);
                y.z = -(Lv[2]*t0 + Lv[6]*t1 + Lv[10]*t2 + Lv[14]*t3);
                y.w = -(Lv[3]*t0 + Lv[7]*t1 + Lv[11]*t2 + Lv[15]*t3);
                x1 = y;
            }
            qf[u][cs] = (f16x8){(f16)(x0.x*sc2), (f16)(x0.y*sc2), (f16)(x0.z*sc2), (f16)(x0.w*sc2),
                                (f16)(x1.x*sc2), (f16)(x1.y*sc2), (f16)(x1.z*sc2), (f16)(x1.w*sc2)};
        }
    }

    f32x4 oacc[2][8];
    #pragma unroll
    for (int u = 0; u < 2; ++u)
        #pragma unroll
        for (int cb = 0; cb < 8; ++cb) oacc[u][cb] = (f32x4){0.f, 0.f, 0.f, 0.f};
    float mrun[2] = {-1e30f, -1e30f}, lrun[2] = {0.f, 0.f};

    for (int it2 = 0; it2 < 8; ++it2) {               // this wave's 64-key chunks
        const int it = w * 8 + it2;                   // wave w streams keys [w*512, w*512+512)
        const f16* kp = kbh + (size_t)it * 16 * 512;
        f16x8 kf[4][4];
        #pragma unroll
        for (int g = 0; g < 4; ++g)
            #pragma unroll
            for (int cs = 0; cs < 4; ++cs)
                kf[g][cs] = *(const f16x8*)(kp + (g * 4 + cs) * 512 + lane * 8);

        f32x4 s[2][4];
        #pragma unroll
        for (int u = 0; u < 2; ++u)
            #pragma unroll
            for (int g = 0; g < 4; ++g) s[u][g] = (f32x4){0.f, 0.f, 0.f, 0.f};
        #pragma unroll
        for (int g = 0; g < 4; ++g)
            #pragma unroll
            for (int cs = 0; cs < 4; ++cs) {
                s[0][g] = __builtin_amdgcn_mfma_f32_16x16x32_f16(kf[g][cs], qf[0][cs], s[0][g], 0, 0, 0);
                s[1][g] = __builtin_amdgcn_mfma_f32_16x16x32_f16(kf[g][cs], qf[1][cs], s[1][g], 0, 0, 0);
            }

        const f16* vp = vbh + (size_t)it * 2 * 8 * 512;
        f16x8 vf[2][8];
        #pragma unroll
        for (int k2 = 0; k2 < 2; ++k2)
            #pragma unroll
            for (int cb = 0; cb < 8; ++cb)
                vf[k2][cb] = *(const f16x8*)(vp + (k2 * 8 + cb) * 512 + lane * 8);

        // exp2-domain online softmax; oacc rescale skipped when max didn't increase
        f16x8 pf[2][2];
        #pragma unroll
        for (int u = 0; u < 2; ++u) {
            float mx = -1e30f;
            #pragma unroll
            for (int g = 0; g < 4; ++g)
                mx = fmaxf(mx, fmaxf(fmaxf(s[u][g].x, s[u][g].y), fmaxf(s[u][g].z, s[u][g].w)));
            mx = fmaxf(mx, __shfl_xor(mx, 16, 64));
            mx = fmaxf(mx, __shfl_xor(mx, 32, 64));
            float mnew = fmaxf(mrun[u], mx);
            float alpha = exp2f(mrun[u] - mnew);
            float p[16], rs = 0.f;
            #pragma unroll
            for (int g = 0; g < 4; ++g) {
                p[g*4+0] = exp2f(s[u][g].x - mnew);
                p[g*4+1] = exp2f(s[u][g].y - mnew);
                p[g*4+2] = exp2f(s[u][g].z - mnew);
                p[g*4+3] = exp2f(s[u][g].w - mnew);
                rs += (p[g*4+0] + p[g*4+1]) + (p[g*4+2] + p[g*4+3]);
            }
            rs += __shfl_xor(rs, 16, 64);
            rs += __shfl_xor(rs, 32, 64);
            lrun[u] = alpha * lrun[u] + rs;
            if (mx > mrun[u]) {            // wave-uniform: rescale only when max moved
                #pragma unroll
                for (int cb = 0; cb < 8; ++cb) oacc[u][cb] *= alpha;
            }
            mrun[u] = mnew;
            pf[u][0] = (f16x8){(f16)p[0],(f16)p[1],(f16)p[2],(f16)p[3],(f16)p[4],(f16)p[5],(f16)p[6],(f16)p[7]};
            pf[u][1] = (f16x8){(f16)p[8],(f16)p[9],(f16)p[10],(f16)p[11],(f16)p[12],(f16)p[13],(f16)p[14],(f16)p[15]};
        }
        #pragma unroll
        for (int k2 = 0; k2 < 2; ++k2)
            #pragma unroll
            for (int cb = 0; cb < 8; ++cb) {
                oacc[0][cb] = __builtin_amdgcn_mfma_f32_16x16x32_f16(vf[k2][cb], pf[0][k2], oacc[0][cb], 0, 0, 0);
                oacc[1][cb] = __builtin_amdgcn_mfma_f32_16x16x32_f16(vf[k2][cb], pf[1][k2], oacc[1][cb], 0, 0, 0);
            }
    }

    // ---- split-K combine: wave w parks the half it does NOT combine ----
    // wave 0 combines c[0,64) (cb 0..3), parks cb 4..7; wave 1 combines c[64,128), parks cb 0..3.
    #pragma unroll
    for (int u = 0; u < 2; ++u) {
        int ql = u * 16 + lq;
        if (quad == 0) { MLx[w][0][ql] = mrun[u]; MLx[w][1][ql] = lrun[u]; }
        #pragma unroll
        for (int i = 0; i < 4; ++i) {
            int cb = (w == 0) ? (4 + i) : i;
            int cloc = cb * 16 + quad * 4 - (w == 0 ? 64 : 0);
            *(f32x4*)&OX[w][ql][cloc] = oacc[u][cb];
        }
    }
    __syncthreads();
    const int p = 1 - w;
    #pragma unroll
    for (int u = 0; u < 2; ++u) {
        int ql = u * 16 + lq;
        float mo = mrun[u], lo = lrun[u];
        float mp = MLx[p][0][ql], lp = MLx[p][1][ql];
        float mt = fmaxf(mo, mp);
        float ao = exp2f(mo - mt), ap = exp2f(mp - mt);
        float invl = 1.0f / (ao * lo + ap * lp);
        const float* Lr = Lm + ((size_t)b * NSEQ + q0 + ql) * 16;
        float* ob = out + ((size_t)bh * NSEQ + q0 + ql) * CD;
        #pragma unroll
        for (int i = 0; i < 4; ++i) {
            int cb = (w == 0) ? i : (4 + i);
            int c0 = cb * 16 + quad * 4;
            f32x4 oth = *(const f32x4*)&OX[p][ql][c0 - (w == 0 ? 0 : 64)];
            f32x4 mine = oacc[u][cb];
            float o0 = (ao*mine.x + ap*oth.x) * invl;
            float o1 = (ao*mine.y + ap*oth.y) * invl;
            float o2 = (ao*mine.z + ap*oth.z) * invl;
            float o3 = (ao*mine.w + ap*oth.w) * invl;
            float4 r;
            if (c0 >= 8) {
                r.x = Lr[0] *o0 + Lr[1] *o1 + Lr[2] *o2 + Lr[3] *o3;
                r.y = Lr[4] *o0 + Lr[5] *o1 + Lr[6] *o2 + Lr[7] *o3;
                r.z = Lr[8] *o0 + Lr[9] *o1 + Lr[10]*o2 + Lr[11]*o3;
                r.w = Lr[12]*o0 + Lr[13]*o1 + Lr[14]*o2 + Lr[15]*o3;
            } else {
                r.x = o0; r.y = o1; r.z = o2; r.w = o3;
            }
            *(float4*)(ob + c0) = r;
        }
    }
}

extern "C" void kernel_launch(void* const* d_in, const int* in_sizes, int n_in,
                              void* d_out, int out_size, void* d_ws, size_t ws_size,
                              hipStream_t stream) {
    const float* q = (const float*)d_in[0];
    const float* k = (const float*)d_in[1];
    const float* v = (const float*)d_in[2];
    const float* L = (const float*)d_in[3];
    float* o = (float*)d_out;
    f16* khs = (f16*)d_ws;                       // 16.78 MB
    f16* vhs = khs + (size_t)64 * 131072;        // 16.78 MB
    dim3 grid1(64, 16);
    ipa_pre<<<grid1, 256, 0, stream>>>(k, v, L, khs, vhs);
    ipa_attn<<<2048, 128, 0, stream>>>(q, khs, vhs, L, o);
}

// Round 7
// 211.757 us; speedup vs baseline: 2.6028x; 2.6028x over previous
//
#include <hip/hip_runtime.h>
#include <math.h>

typedef _Float16 f16;
typedef _Float16 f16x4 __attribute__((ext_vector_type(4)));
typedef _Float16 f16x8 __attribute__((ext_vector_type(8)));
typedef float    f32x4 __attribute__((ext_vector_type(4)));

#define NSEQ 1024
#define CD   128
#define LT   136   // pre-kernel LDS f16 row stride (272 B = 17*16 B, keeps b128 alignment)

// khs: [bh][g16 0..63][cs 0..3][lane 0..63][j 0..7]   (131072 f16 per bh)
// vhs: [bh][k32 0..31][cb 0..7][lane 0..63][j 0..7]
// Both are exact MFMA fragment order: a wave's frag load = base + lane*16B (coalesced 1KB).

__global__ __launch_bounds__(256)
void ipa_pre(const float* __restrict__ kg, const float* __restrict__ vg,
             const float* __restrict__ Lm, f16* __restrict__ khs, f16* __restrict__ vhs)
{
    __shared__ float LL[64 * 16];
    __shared__ __align__(16) f16 Kt[64 * LT];
    __shared__ __align__(16) f16 Vt[64 * LT];
    const int bx = blockIdx.x, nt = blockIdx.y, tid = threadIdx.x;
    const int bh = ((bx & 7) << 3) | (bx >> 3);   // XCD x <-> bh 8x..8x+7 (matches attn)
    const int b  = bh >> 3;
    const float* Lb = Lm + ((size_t)b * NSEQ + nt * 64) * 16;
    for (int t = tid; t < 64 * 16; t += 256) LL[t] = Lb[t];
    __syncthreads();

    const size_t base = ((size_t)bh * NSEQ + nt * 64) * CD;
    #pragma unroll
    for (int it = 0; it < 8; ++it) {
        int g = it * 256 + tid;
        int row = g >> 5, cg = g & 31;
        size_t idx = base + row * CD + cg * 4;
        const float* Lr = &LL[row * 16];
        float4 xk = *(const float4*)(kg + idx);
        float4 xv = *(const float4*)(vg + idx);
        float4 yk = xk, yv = xv;
        if (cg >= 2) {
            float t0 = xk.x, t1 = -xk.y, t2 = -xk.z, t3 = -xk.w;   // K: M = L^T eta
            yk.x = Lr[0]*t0 + Lr[4]*t1 + Lr[8] *t2 + Lr[12]*t3;
            yk.y = Lr[1]*t0 + Lr[5]*t1 + Lr[9] *t2 + Lr[13]*t3;
            yk.z = Lr[2]*t0 + Lr[6]*t1 + Lr[10]*t2 + Lr[14]*t3;
            yk.w = Lr[3]*t0 + Lr[7]*t1 + Lr[11]*t2 + Lr[15]*t3;
            t0 = xv.x; t1 = -xv.y; t2 = -xv.z; t3 = -xv.w;         // V: M = eta L^T eta
            yv.x =  (Lr[0]*t0 + Lr[4]*t1 + Lr[8] *t2 + Lr[12]*t3);
            yv.y = -(Lr[1]*t0 + Lr[5]*t1 + Lr[9] *t2 + Lr[13]*t3);
            yv.z = -(Lr[2]*t0 + Lr[6]*t1 + Lr[10]*t2 + Lr[14]*t3);
            yv.w = -(Lr[3]*t0 + Lr[7]*t1 + Lr[11]*t2 + Lr[15]*t3);
        }
        f16x4 hk = {(f16)yk.x, (f16)yk.y, (f16)yk.z, (f16)yk.w};
        f16x4 hv = {(f16)yv.x, (f16)yv.y, (f16)yv.z, (f16)yv.w};
        *(f16x4*)&Kt[row * LT + cg * 4] = hk;
        *(f16x4*)&Vt[row * LT + cg * 4] = hv;
    }
    __syncthreads();

    // staged K out (b128 LDS read -> fully coalesced global store)
    f16* kout = khs + (size_t)bh * 131072 + (size_t)nt * 4 * 4 * 512;
    #pragma unroll
    for (int it = 0; it < 4; ++it) {
        int slot = it * 256 + tid;                 // (g16l, cs, L)
        int g16l = slot >> 8, cs = (slot >> 6) & 3, L = slot & 63;
        int lq = L & 15, quad = L >> 4;
        int keyl = ((g16l >> 1) << 5) + ((lq >> 2) << 3) + ((g16l & 1) << 2) + (lq & 3);
        f16x8 kv = *(const f16x8*)&Kt[keyl * LT + cs * 32 + quad * 8];
        *(f16x8*)(kout + (g16l * 4 + cs) * 512 + L * 8) = kv;
    }
    // staged V^T out (scalar LDS column reads -> coalesced global store)
    f16* vout = vhs + (size_t)bh * 131072 + (size_t)nt * 2 * 8 * 512;
    #pragma unroll
    for (int it = 0; it < 4; ++it) {
        int slot = it * 256 + tid;                 // (k32l, cb, L)
        int k32l = slot >> 9, cb = (slot >> 6) & 7, L = slot & 63;
        int lq = L & 15, quad = L >> 4;
        int c = cb * 16 + lq;
        f16x8 o;
        #pragma unroll
        for (int j = 0; j < 8; ++j)
            o[j] = Vt[(k32l * 32 + quad * 8 + j) * LT + c];
        *(f16x8*)(vout + (k32l * 8 + cb) * 512 + L * 8) = o;
    }
}

// ------- attention: split-K streaming (2 waves/block, keys halved), LDS combine -------
// __launch_bounds__(128,2): bound 4 forced VGPR cap 128 -> scratch spill (R6: 1.8 GB HBM,
// 450 us). Body needs ~128 live VGPRs; cap 256 lets allocator keep frags resident, and
// 128 VGPR already permits 4 waves/SIMD.
__global__ __launch_bounds__(128, 2)
void ipa_attn(const float* __restrict__ qg, const f16* __restrict__ khs,
              const f16* __restrict__ vhs, const float* __restrict__ Lm,
              float* __restrict__ out)
{
    __shared__ float OX[2][32][68];    // channel-half exchange [wave][qlocal][c(+pad)]
    __shared__ float MLx[2][2][32];    // [wave][m/l][qlocal]

    const int n = blockIdx.x;                          // 0..2047
    const int bh = ((n & 7) << 3) | ((n >> 3) & 7);    // XCD n%8 owns bh 8x..8x+7
    const int b  = bh >> 3;
    const int tid = threadIdx.x;
    const int w = tid >> 6, lane = tid & 63, lq = lane & 15, quad = lane >> 4;
    const int q0 = (n >> 6) * 32;                      // 32 q-groups per bh
    const f16* kbh = khs + (size_t)bh * 131072;
    const f16* vbh = vhs + (size_t)bh * 131072;
    const float sc2 = 0.12751744154226873f;            // (1/sqrt(128)) * log2(e)

    // ---- Q: load fp32, transform (M = eta L^T eta) per-lane, scale, make frags ----
    f16x8 qf[2][4];
    #pragma unroll
    for (int u = 0; u < 2; ++u) {
        int qrow = q0 + u * 16 + lq;
        const float* Lr = Lm + ((size_t)b * NSEQ + qrow) * 16;
        const float* qp = qg + ((size_t)bh * NSEQ + qrow) * CD;
        float Lv[16];
        #pragma unroll
        for (int i = 0; i < 4; ++i) *(float4*)&Lv[i*4] = *(const float4*)(Lr + i*4);
        #pragma unroll
        for (int cs = 0; cs < 4; ++cs) {
            int c0 = cs * 32 + quad * 8;
            float4 x0 = *(const float4*)(qp + c0);
            float4 x1 = *(const float4*)(qp + c0 + 4);
            if (c0 >= 8) {
                float t0 = x0.x, t1 = -x0.y, t2 = -x0.z, t3 = -x0.w;
                float4 y;
                y.x =  (Lv[0]*t0 + Lv[4]*t1 + Lv[8] *t2 + Lv[12]*t3);
                y.y = -(Lv[1]*t0 + Lv[5]*t1 + Lv[9] *t2 + Lv[13]*t3);
                y.z = -(Lv[2]*t0 + Lv[6]*t1 + Lv[10]*t2 + Lv[14]*t3);
                y.w = -(Lv[3]*t0 + Lv[7]*t1 + Lv[11]*t2 + Lv[15]*t3);
                x0 = y;
                t0 = x1.x; t1 = -x1.y; t2 = -x1.z; t3 = -x1.w;
                y.x =  (Lv[0]*t0 + Lv[4]*t1 + Lv[8] *t2 + Lv[12]*t3);
                y.y = -(Lv[1]*t0 + Lv[5]*t1 + Lv[9] *t2 + Lv[13]*t3);
                y.z = -(Lv[2]*t0 + Lv[6]*t1 + Lv[10]*t2 + Lv[14]*t3);
                y.w = -(Lv[3]*t0 + Lv[7]*t1 + Lv[11]*t2 + Lv[15]*t3);
                x1 = y;
            }
            qf[u][cs] = (f16x8){(f16)(x0.x*sc2), (f16)(x0.y*sc2), (f16)(x0.z*sc2), (f16)(x0.w*sc2),
                                (f16)(x1.x*sc2), (f16)(x1.y*sc2), (f16)(x1.z*sc2), (f16)(x1.w*sc2)};
        }
    }

    f32x4 oacc[2][8];
    #pragma unroll
    for (int u = 0; u < 2; ++u)
        #pragma unroll
        for (int cb = 0; cb < 8; ++cb) oacc[u][cb] = (f32x4){0.f, 0.f, 0.f, 0.f};
    float mrun[2] = {-1e30f, -1e30f}, lrun[2] = {0.f, 0.f};

    for (int it2 = 0; it2 < 8; ++it2) {               // this wave's 64-key chunks
        const int it = w * 8 + it2;                   // wave w streams keys [w*512, w*512+512)
        const f16* kp = kbh + (size_t)it * 16 * 512;
        f16x8 kf[4][4];
        #pragma unroll
        for (int g = 0; g < 4; ++g)
            #pragma unroll
            for (int cs = 0; cs < 4; ++cs)
                kf[g][cs] = *(const f16x8*)(kp + (g * 4 + cs) * 512 + lane * 8);

        f32x4 s[2][4];
        #pragma unroll
        for (int u = 0; u < 2; ++u)
            #pragma unroll
            for (int g = 0; g < 4; ++g) s[u][g] = (f32x4){0.f, 0.f, 0.f, 0.f};
        #pragma unroll
        for (int g = 0; g < 4; ++g)
            #pragma unroll
            for (int cs = 0; cs < 4; ++cs) {
                s[0][g] = __builtin_amdgcn_mfma_f32_16x16x32_f16(kf[g][cs], qf[0][cs], s[0][g], 0, 0, 0);
                s[1][g] = __builtin_amdgcn_mfma_f32_16x16x32_f16(kf[g][cs], qf[1][cs], s[1][g], 0, 0, 0);
            }

        const f16* vp = vbh + (size_t)it * 2 * 8 * 512;
        f16x8 vf[2][8];
        #pragma unroll
        for (int k2 = 0; k2 < 2; ++k2)
            #pragma unroll
            for (int cb = 0; cb < 8; ++cb)
                vf[k2][cb] = *(const f16x8*)(vp + (k2 * 8 + cb) * 512 + lane * 8);

        // exp2-domain online softmax; oacc rescale skipped when max didn't increase
        f16x8 pf[2][2];
        #pragma unroll
        for (int u = 0; u < 2; ++u) {
            float mx = -1e30f;
            #pragma unroll
            for (int g = 0; g < 4; ++g)
                mx = fmaxf(mx, fmaxf(fmaxf(s[u][g].x, s[u][g].y), fmaxf(s[u][g].z, s[u][g].w)));
            mx = fmaxf(mx, __shfl_xor(mx, 16, 64));
            mx = fmaxf(mx, __shfl_xor(mx, 32, 64));
            float mnew = fmaxf(mrun[u], mx);
            float alpha = exp2f(mrun[u] - mnew);
            float p[16], rs = 0.f;
            #pragma unroll
            for (int g = 0; g < 4; ++g) {
                p[g*4+0] = exp2f(s[u][g].x - mnew);
                p[g*4+1] = exp2f(s[u][g].y - mnew);
                p[g*4+2] = exp2f(s[u][g].z - mnew);
                p[g*4+3] = exp2f(s[u][g].w - mnew);
                rs += (p[g*4+0] + p[g*4+1]) + (p[g*4+2] + p[g*4+3]);
            }
            rs += __shfl_xor(rs, 16, 64);
            rs += __shfl_xor(rs, 32, 64);
            lrun[u] = alpha * lrun[u] + rs;
            if (mx > mrun[u]) {            // wave-uniform: rescale only when max moved
                #pragma unroll
                for (int cb = 0; cb < 8; ++cb) oacc[u][cb] *= alpha;
            }
            mrun[u] = mnew;
            pf[u][0] = (f16x8){(f16)p[0],(f16)p[1],(f16)p[2],(f16)p[3],(f16)p[4],(f16)p[5],(f16)p[6],(f16)p[7]};
            pf[u][1] = (f16x8){(f16)p[8],(f16)p[9],(f16)p[10],(f16)p[11],(f16)p[12],(f16)p[13],(f16)p[14],(f16)p[15]};
        }
        #pragma unroll
        for (int k2 = 0; k2 < 2; ++k2)
            #pragma unroll
            for (int cb = 0; cb < 8; ++cb) {
                oacc[0][cb] = __builtin_amdgcn_mfma_f32_16x16x32_f16(vf[k2][cb], pf[0][k2], oacc[0][cb], 0, 0, 0);
                oacc[1][cb] = __builtin_amdgcn_mfma_f32_16x16x32_f16(vf[k2][cb], pf[1][k2], oacc[1][cb], 0, 0, 0);
            }
    }

    // ---- split-K combine: wave w parks the half it does NOT combine ----
    #pragma unroll
    for (int u = 0; u < 2; ++u) {
        int ql = u * 16 + lq;
        if (quad == 0) { MLx[w][0][ql] = mrun[u]; MLx[w][1][ql] = lrun[u]; }
        #pragma unroll
        for (int i = 0; i < 4; ++i) {
            int cb = (w == 0) ? (4 + i) : i;
            int cloc = cb * 16 + quad * 4 - (w == 0 ? 64 : 0);
            *(f32x4*)&OX[w][ql][cloc] = oacc[u][cb];
        }
    }
    __syncthreads();
    const int p = 1 - w;
    #pragma unroll
    for (int u = 0; u < 2; ++u) {
        int ql = u * 16 + lq;
        float mo = mrun[u], lo = lrun[u];
        float mp = MLx[p][0][ql], lp = MLx[p][1][ql];
        float mt = fmaxf(mo, mp);
        float ao = exp2f(mo - mt), ap = exp2f(mp - mt);
        float invl = 1.0f / (ao * lo + ap * lp);
        const float* Lr = Lm + ((size_t)b * NSEQ + q0 + ql) * 16;
        float* ob = out + ((size_t)bh * NSEQ + q0 + ql) * CD;
        #pragma unroll
        for (int i = 0; i < 4; ++i) {
            int cb = (w == 0) ? i : (4 + i);
            int c0 = cb * 16 + quad * 4;
            f32x4 oth = *(const f32x4*)&OX[p][ql][c0 - (w == 0 ? 0 : 64)];
            f32x4 mine = oacc[u][cb];
            float o0 = (ao*mine.x + ap*oth.x) * invl;
            float o1 = (ao*mine.y + ap*oth.y) * invl;
            float o2 = (ao*mine.z + ap*oth.z) * invl;
            float o3 = (ao*mine.w + ap*oth.w) * invl;
            float4 r;
            if (c0 >= 8) {
                r.x = Lr[0] *o0 + Lr[1] *o1 + Lr[2] *o2 + Lr[3] *o3;
                r.y = Lr[4] *o0 + Lr[5] *o1 + Lr[6] *o2 + Lr[7] *o3;
                r.z = Lr[8] *o0 + Lr[9] *o1 + Lr[10]*o2 + Lr[11]*o3;
                r.w = Lr[12]*o0 + Lr[13]*o1 + Lr[14]*o2 + Lr[15]*o3;
            } else {
                r.x = o0; r.y = o1; r.z = o2; r.w = o3;
            }
            *(float4*)(ob + c0) = r;
        }
    }
}

extern "C" void kernel_launch(void* const* d_in, const int* in_sizes, int n_in,
                              void* d_out, int out_size, void* d_ws, size_t ws_size,
                              hipStream_t stream) {
    const float* q = (const float*)d_in[0];
    const float* k = (const float*)d_in[1];
    const float* v = (const float*)d_in[2];
    const float* L = (const float*)d_in[3];
    float* o = (float*)d_out;
    f16* khs = (f16*)d_ws;                       // 16.78 MB
    f16* vhs = khs + (size_t)64 * 131072;        // 16.78 MB
    dim3 grid1(64, 16);
    ipa_pre<<<grid1, 256, 0, stream>>>(k, v, L, khs, vhs);
    ipa_attn<<<2048, 128, 0, stream>>>(q, khs, vhs, L, o);
}